// Round 1
// baseline (485.598 us; speedup 1.0000x reference)
//
#include <hip/hip_runtime.h>
#include <math.h>

#define BATCH   8192
#define NSITES  128
#define BOND    64
#define NBULK   126          // N_SITES - 2
#define WPB     16           // waves (= batch elements) per block
#define TPB     (WPB * 64)
#define SITE_ELTS (BOND * 2 * BOND)   // 8192 floats = 32 KB per site

__global__ __launch_bounds__(TPB, 2) void mps_logamp_fp32(
    const int*   __restrict__ cfg,    // (8192, 128)
    const float* __restrict__ left,   // (1, 2, 64)
    const float* __restrict__ bulk,   // (126, 64, 2, 64)
    const float* __restrict__ right,  // (64, 2, 1)
    float*       __restrict__ out)    // (8192,)
{
    __shared__ float Abuf[2][SITE_ELTS];   // 64 KB double-buffered site slice
    __shared__ float envs[WPB][BOND];      // 4 KB env broadcast buffers
    __shared__ int   cfgs[WPB * NSITES];   // 8 KB config rows for this block

    const int t = threadIdx.x;
    const int w = t >> 6;        // wave id = local batch row
    const int l = t & 63;        // lane = bond index j
    const int bbase = blockIdx.x * WPB;
    const int b = bbase + w;

    // ---- stage config rows (2048 ints, 2 per thread) ----
    cfgs[t]       = cfg[bbase * NSITES + t];
    cfgs[t + TPB] = cfg[bbase * NSITES + t + TPB];

    // ---- stage bulk site 0 into Abuf[0] (2 float4 per thread) ----
    {
        const float4* src = (const float4*)bulk;
        float4* dst = (float4*)(&Abuf[0][0]);
        dst[t]       = src[t];
        dst[t + TPB] = src[t + TPB];
    }
    __syncthreads();

    // ---- initial env from left tensor ----
    const int c0 = cfgs[w * NSITES + 0];
    float e = left[c0 * BOND + l];
    float m = fabsf(e);
    #pragma unroll
    for (int k = 32; k; k >>= 1) m = fmaxf(m, __shfl_xor(m, k));
    m = fmaxf(m, 1e-30f);
    e = e / m;
    float ls = logf(m);
    envs[w][l] = e;            // wave-private, in-order LDS: no barrier needed

    // ---- main chain over 126 bulk sites ----
    for (int s = 0; s < NBULK; ++s) {
        const int cur = s & 1;
        const int nxt = cur ^ 1;
        const bool pf = (s + 1 < NBULK);

        // T14 split staging: issue next-site global loads early...
        float4 p0, p1;
        if (pf) {
            const float4* src = (const float4*)(bulk + (size_t)(s + 1) * SITE_ELTS);
            p0 = src[t];
            p1 = src[t + TPB];
        }

        // ...compute current site while they fly
        const int v = cfgs[w * NSITES + (s + 1)];
        const float* Ap = &Abuf[cur][v * BOND + l];   // A[i][v][l], i-stride 128
        const float* ev = &envs[w][0];
        float acc = 0.0f;
        #pragma unroll
        for (int i = 0; i < BOND; i += 4) {
            const float4 e4 = *(const float4*)(ev + i);   // wave-uniform -> broadcast
            acc = fmaf(e4.x, Ap[(i + 0) * 128], acc);
            acc = fmaf(e4.y, Ap[(i + 1) * 128], acc);
            acc = fmaf(e4.z, Ap[(i + 2) * 128], acc);
            acc = fmaf(e4.w, Ap[(i + 3) * 128], acc);
        }

        // per-step max-normalization + log accumulation (matches reference)
        float mm = fabsf(acc);
        #pragma unroll
        for (int k = 32; k; k >>= 1) mm = fmaxf(mm, __shfl_xor(mm, k));
        mm = fmaxf(mm, 1e-30f);
        acc = acc / mm;
        ls += logf(mm);

        // ...land the staged tile into the free buffer
        if (pf) {
            float4* dst = (float4*)(&Abuf[nxt][0]);
            dst[t]       = p0;
            dst[t + TPB] = p1;
        }
        envs[w][l] = acc;      // wave-private
        e = acc;
        __syncthreads();       // protects A buffers both directions
    }

    // ---- final contraction with right tensor ----
    const int vl = cfgs[w * NSITES + (NSITES - 1)];
    float p = e * right[l * 2 + vl];
    #pragma unroll
    for (int k = 32; k; k >>= 1) p += __shfl_xor(p, k);
    const float am = fmaxf(fabsf(p), 1e-30f);
    if (l == 0) out[b] = 2.0f * (ls + logf(am));
}

extern "C" void kernel_launch(void* const* d_in, const int* in_sizes, int n_in,
                              void* d_out, int out_size, void* d_ws, size_t ws_size,
                              hipStream_t stream) {
    const int*   cfg   = (const int*)d_in[0];
    const float* left  = (const float*)d_in[1];
    const float* bulk  = (const float*)d_in[2];
    const float* right = (const float*)d_in[3];
    float*       out   = (float*)d_out;

    const int blocks = BATCH / WPB;   // 512
    hipLaunchKernelGGL(mps_logamp_fp32, dim3(blocks), dim3(TPB), 0, stream,
                       cfg, left, bulk, right, out);
}

// Round 2
// 280.571 us; speedup vs baseline: 1.7307x; 1.7307x over previous
//
#include <hip/hip_runtime.h>
#include <math.h>
#include <stdint.h>

typedef __attribute__((ext_vector_type(8))) short bf16x8;
typedef __attribute__((ext_vector_type(4))) float f32x4;
typedef __attribute__((ext_vector_type(4))) int   i32x4;
typedef __attribute__((ext_vector_type(2))) int   i32x2;

#define NSITES 128
#define NBULK  126
#define BOND   64
#define BATCH  8192

// ---- ws / LDS W image: per site, 3 bf16 terms of W^T[j][r], rows padded ----
#define ROW_B   272                      // 136 bf16 per j-row (128 used + pad), 16B-aligned
#define TERM_B  (64 * ROW_B)             // 17408
#define SITE_B  (3 * TERM_B)             // 52224
#define NCHUNK  (SITE_B / 1024)          // 51 global_load_lds dwordx4 wave-chunks

// ---- LDS layout ----
#define ENV_ROW  280                     // 140 bf16 per (term,b) row -> conflict-free b64
#define ENV_TERM (16 * ENV_ROW)          // 4480
#define ENV_GRP  (3 * ENV_TERM)          // 13440
#define ENV_BASE (2 * SITE_B)            // 104448 (after double-buffered W)
#define MAX_BASE (ENV_BASE + 2 * ENV_GRP)// 131328
#define SMEM_SZ  (MAX_BASE + 512)        // 131840 <= 160 KiB

__device__ __forceinline__ uint bf16hi(float x) {  // RNE bf16, kept in TOP 16 bits
    uint u = __float_as_uint(x);
    return (u + 0x7fffu + ((u >> 16) & 1u)) & 0xffff0000u;
}
__device__ __forceinline__ void split3(float x, uint& h1, uint& h2, uint& h3) {
    h1 = bf16hi(x);
    float r1 = x - __uint_as_float(h1);   // exact (Sterbenz)
    h2 = bf16hi(r1);
    float r2 = r1 - __uint_as_float(h2);  // exact
    h3 = bf16hi(r2);
}

// ================= pre-pass: split bulk into 3 bf16 planes, W^T layout =================
__global__ void mps_prepass(const float* __restrict__ bulk, uint* __restrict__ wsd) {
    const int t  = threadIdx.x;
    const int s  = blockIdx.x >> 1;
    const int rc = ((blockIdx.x & 1) << 2) | (t >> 6);   // 0..7, chunk of 16 r's
    const int j  = t & 63;
    const float* src = bulk + (size_t)s * 8192 + (size_t)rc * 16 * 64 + j; // flat r*64+j
    uint h1[16], h2[16], h3[16];
    #pragma unroll
    for (int k = 0; k < 16; ++k) split3(src[k * 64], h1[k], h2[k], h3[k]);
    uint* drow = wsd + (size_t)s * (SITE_B / 4) + (size_t)j * (ROW_B / 4) + rc * 8;
    #pragma unroll
    for (int d = 0; d < 8; ++d) {
        drow[d]                  = (h1[2*d] >> 16) | h1[2*d+1];
        drow[d +     TERM_B / 4] = (h2[2*d] >> 16) | h2[2*d+1];
        drow[d + 2 * (TERM_B/4)] = (h3[2*d] >> 16) | h3[2*d+1];
    }
}

// ================= main MFMA kernel =================
__device__ __forceinline__ void stage_site(const char* __restrict__ ws, char* dst,
                                           int site, int w, int l) {
    const char* sp = ws + (size_t)site * SITE_B + (size_t)(l * 16);
    for (int u = w; u < NCHUNK; u += 8)
        __builtin_amdgcn_global_load_lds(
            (const __attribute__((address_space(1))) void*)(sp + (size_t)u * 1024),
            (__attribute__((address_space(3))) void*)(dst + u * 1024), 16, 0, 0);
}

// normalize env, accumulate log, split to 3 bf16 planes, publish to LDS. 2 barriers.
__device__ __forceinline__ void publish_env(float e[4], char* smem,
        int g, int jt, int lg, int lb, float& ls) {
    float mw = fmaxf(fmaxf(fabsf(e[0]), fabsf(e[1])), fmaxf(fabsf(e[2]), fabsf(e[3])));
    mw = fmaxf(mw, __shfl_xor(mw, 16));
    mw = fmaxf(mw, __shfl_xor(mw, 32));
    if (lg == 0) *(float*)(smem + MAX_BASE + g*256 + lb*16 + jt*4) = mw;
    asm volatile("s_waitcnt vmcnt(0)" ::: "memory");  // staged W for next site landed
    __syncthreads();                                   // barrier 1: maxes visible
    f32x4 mv = *(const f32x4*)(smem + MAX_BASE + g*256 + lb*16);
    float m = fmaxf(fmaxf(mv.x, mv.y), fmaxf(mv.z, mv.w));
    m = fmaxf(m, 1e-30f);
    ls += logf(m);
    uint p1[4], p2[4], p3[4];
    #pragma unroll
    for (int r = 0; r < 4; ++r) {
        e[r] = e[r] / m;
        split3(e[r], p1[r], p2[r], p3[r]);
    }
    char* eb = smem + ENV_BASE + g*ENV_GRP + lb*ENV_ROW + (jt*32 + lg*8);
    i32x2 v1; v1.x = (int)((p1[0] >> 16) | p1[1]); v1.y = (int)((p1[2] >> 16) | p1[3]);
    i32x2 v2; v2.x = (int)((p2[0] >> 16) | p2[1]); v2.y = (int)((p2[2] >> 16) | p2[3]);
    i32x2 v3; v3.x = (int)((p3[0] >> 16) | p3[1]); v3.y = (int)((p3[2] >> 16) | p3[3]);
    *(i32x2*)(eb)                = v1;
    *(i32x2*)(eb + ENV_TERM)     = v2;
    *(i32x2*)(eb + 2 * ENV_TERM) = v3;
    __syncthreads();                                   // barrier 2: env visible
}

__global__ __launch_bounds__(512, 2) void mps_main(
    const int*   __restrict__ cfg,
    const float* __restrict__ left,
    const float* __restrict__ right,
    const char*  __restrict__ ws,
    float*       __restrict__ out)
{
    extern __shared__ char smem[];
    const int t  = threadIdx.x;
    const int w  = t >> 6, l = t & 63;
    const int g  = w >> 2;          // group (16 batch rows)
    const int jt = w & 3;           // j-tile of 16
    const int lb = l & 15, lg = l >> 4;
    const int bbase = blockIdx.x * 32 + g * 16;
    const int b = bbase + lb;
    const int jbase = jt * 16 + lg * 4;     // this lane's 4 output j rows
    const int cfgb = b * NSITES;

    stage_site(ws, smem, 0, w, l);          // W for site 0 -> buf 0

    // initial env from left tensor
    const int c0 = cfg[cfgb];
    float e[4];
    #pragma unroll
    for (int r = 0; r < 4; ++r) e[r] = left[c0 * BOND + jbase + r];
    float ls = 0.0f;
    publish_env(e, smem, g, jt, lg, lb, ls);  // also waits site-0 staging

    const int pw[6] = {0, 0, 1, 0, 1, 2};     // W term of product p
    const int pe[6] = {0, 1, 0, 2, 1, 0};     // E term of product p

    for (int s = 0; s < NBULK; ++s) {
        const int buf = s & 1;
        if (s + 1 < NBULK) stage_site(ws, smem + (buf ^ 1) * SITE_B, s + 1, w, l);

        const int  v  = cfg[cfgb + s + 1];
        const int  sh = v << 4;
        const uint M  = v ? 0xffff0000u : 0x0000ffffu;

        const char* wb    = smem + buf * SITE_B + (jt * 16 + lb) * ROW_B + lg * 16;
        const char* ebase = smem + ENV_BASE + g * ENV_GRP + lb * ENV_ROW + lg * 8;

        bf16x8 A[4][3], Bf[4][3];
        #pragma unroll
        for (int ks = 0; ks < 4; ++ks) {
            #pragma unroll
            for (int tm = 0; tm < 3; ++tm) {
                A[ks][tm] = *(const bf16x8*)(wb + tm * TERM_B + ks * 64);
                i32x2 d = *(const i32x2*)(ebase + tm * ENV_TERM + ks * 32);
                int q0 = (int)(((uint)d.x << sh) & M);
                int q1 = (int)(((uint)d.x >> (16 - sh)) & M);
                int q2 = (int)(((uint)d.y << sh) & M);
                int q3 = (int)(((uint)d.y >> (16 - sh)) & M);
                i32x4 qq; qq.x = q0; qq.y = q1; qq.z = q2; qq.w = q3;
                Bf[ks][tm] = __builtin_bit_cast(bf16x8, qq);
            }
        }

        f32x4 acc[4];
        #pragma unroll
        for (int ks = 0; ks < 4; ++ks) { acc[ks].x=0.f; acc[ks].y=0.f; acc[ks].z=0.f; acc[ks].w=0.f; }

        __builtin_amdgcn_s_setprio(1);
        #pragma unroll
        for (int p = 0; p < 6; ++p)
            #pragma unroll
            for (int ks = 0; ks < 4; ++ks)
                acc[ks] = __builtin_amdgcn_mfma_f32_16x16x32_bf16(
                              A[ks][pw[p]], Bf[ks][pe[p]], acc[ks], 0, 0, 0);
        __builtin_amdgcn_s_setprio(0);

        #pragma unroll
        for (int r = 0; r < 4; ++r)
            e[r] = (acc[0][r] + acc[1][r]) + (acc[2][r] + acc[3][r]);

        publish_env(e, smem, g, jt, lg, lb, ls);
    }

    // final contraction with right tensor
    const int vl = cfg[cfgb + NSITES - 1];
    float pr = 0.0f;
    #pragma unroll
    for (int r = 0; r < 4; ++r) pr += e[r] * right[(jbase + r) * 2 + vl];
    pr += __shfl_xor(pr, 16);
    pr += __shfl_xor(pr, 32);
    if (lg == 0) *(float*)(smem + MAX_BASE + g*256 + lb*16 + jt*4) = pr;
    __syncthreads();
    f32x4 pv = *(const f32x4*)(smem + MAX_BASE + g*256 + lb*16);
    float psi  = (pv.x + pv.y) + (pv.z + pv.w);
    float am   = fmaxf(fabsf(psi), 1e-30f);
    float tt   = psi / am;
    float abs2 = fmaxf(tt * tt, 1e-30f);
    float res  = logf(abs2) + 2.0f * (ls + logf(am));
    if (jt == 0 && lg == 0) out[bbase + lb] = res;
}

// ================= fallback fp32 kernel (R0, known-good) =================
#define WPB     16
#define TPB     (WPB * 64)
#define SITE_ELTS (BOND * 2 * BOND)

__global__ __launch_bounds__(TPB, 2) void mps_logamp_fp32(
    const int*   __restrict__ cfg, const float* __restrict__ left,
    const float* __restrict__ bulk, const float* __restrict__ right,
    float* __restrict__ out)
{
    __shared__ float Abuf[2][SITE_ELTS];
    __shared__ float envs[WPB][BOND];
    __shared__ int   cfgs[WPB * NSITES];
    const int t = threadIdx.x;
    const int w = t >> 6, l = t & 63;
    const int bbase = blockIdx.x * WPB;
    const int b = bbase + w;
    cfgs[t] = cfg[bbase * NSITES + t];
    cfgs[t + TPB] = cfg[bbase * NSITES + t + TPB];
    { const float4* src = (const float4*)bulk; float4* dst = (float4*)(&Abuf[0][0]);
      dst[t] = src[t]; dst[t + TPB] = src[t + TPB]; }
    __syncthreads();
    const int c0 = cfgs[w * NSITES];
    float e = left[c0 * BOND + l];
    float m = fabsf(e);
    #pragma unroll
    for (int k = 32; k; k >>= 1) m = fmaxf(m, __shfl_xor(m, k));
    m = fmaxf(m, 1e-30f);
    e = e / m;
    float ls = logf(m);
    envs[w][l] = e;
    for (int s = 0; s < NBULK; ++s) {
        const int cur = s & 1, nxt = cur ^ 1;
        const bool pf = (s + 1 < NBULK);
        float4 p0, p1;
        if (pf) { const float4* src = (const float4*)(bulk + (size_t)(s + 1) * SITE_ELTS);
                  p0 = src[t]; p1 = src[t + TPB]; }
        const int v = cfgs[w * NSITES + (s + 1)];
        const float* Ap = &Abuf[cur][v * BOND + l];
        const float* ev = &envs[w][0];
        float acc = 0.0f;
        #pragma unroll
        for (int i = 0; i < BOND; i += 4) {
            const float4 e4 = *(const float4*)(ev + i);
            acc = fmaf(e4.x, Ap[(i + 0) * 128], acc);
            acc = fmaf(e4.y, Ap[(i + 1) * 128], acc);
            acc = fmaf(e4.z, Ap[(i + 2) * 128], acc);
            acc = fmaf(e4.w, Ap[(i + 3) * 128], acc);
        }
        float mm = fabsf(acc);
        #pragma unroll
        for (int k = 32; k; k >>= 1) mm = fmaxf(mm, __shfl_xor(mm, k));
        mm = fmaxf(mm, 1e-30f);
        acc = acc / mm;
        ls += logf(mm);
        if (pf) { float4* dst = (float4*)(&Abuf[nxt][0]); dst[t] = p0; dst[t + TPB] = p1; }
        envs[w][l] = acc;
        e = acc;
        __syncthreads();
    }
    const int vl = cfgs[w * NSITES + (NSITES - 1)];
    float p = e * right[l * 2 + vl];
    #pragma unroll
    for (int k = 32; k; k >>= 1) p += __shfl_xor(p, k);
    const float am = fmaxf(fabsf(p), 1e-30f);
    if (l == 0) out[b] = 2.0f * (ls + logf(am));
}

extern "C" void kernel_launch(void* const* d_in, const int* in_sizes, int n_in,
                              void* d_out, int out_size, void* d_ws, size_t ws_size,
                              hipStream_t stream) {
    const int*   cfg   = (const int*)d_in[0];
    const float* left  = (const float*)d_in[1];
    const float* bulk  = (const float*)d_in[2];
    const float* right = (const float*)d_in[3];
    float*       out   = (float*)d_out;

    const size_t need = (size_t)NBULK * SITE_B;   // 6,580,224 B
    if (ws_size >= need) {
        hipFuncSetAttribute((const void*)mps_main,
                            hipFuncAttributeMaxDynamicSharedMemorySize, SMEM_SZ);
        hipLaunchKernelGGL(mps_prepass, dim3(252), dim3(256), 0, stream,
                           bulk, (uint*)d_ws);
        hipLaunchKernelGGL(mps_main, dim3(BATCH / 32), dim3(512), SMEM_SZ, stream,
                           cfg, left, right, (const char*)d_ws, out);
    } else {
        hipLaunchKernelGGL(mps_logamp_fp32, dim3(BATCH / WPB), dim3(TPB), 0, stream,
                           cfg, left, bulk, right, out);
    }
}

// Round 3
// 122.458 us; speedup vs baseline: 3.9654x; 2.2912x over previous
//
#include <hip/hip_runtime.h>
#include <math.h>
#include <stdint.h>

typedef __attribute__((ext_vector_type(8))) short bf16x8;
typedef __attribute__((ext_vector_type(4))) float f32x4;
typedef __attribute__((ext_vector_type(4))) int   i32x4;
typedef __attribute__((ext_vector_type(2))) int   i32x2;

#define NSITES 128
#define NBULK  126
#define BOND   64
#define BATCH  8192

#define WSITE     49152                         // 2v * 3tm * 64j * 128B per site
#define WMASK_OFF ((size_t)NBULK * (size_t)WSITE)   // 6193152
#define WS_NEED   (WMASK_OFF + (size_t)BATCH * 16)  // 6324224

#define EBUF0   98304                           // after 2x48KB W buffers
#define EBUF_SZ 12288                           // 2g * 3tm * 16b * 128B
#define RED_OFF 122880                          // 512B reduce buffer
#define SMEM_SZ 123392

#define MFMA_BF16 __builtin_amdgcn_mfma_f32_16x16x32_bf16

// ============ prepass 1: split bulk into 3 trunc-bf16 planes, swizzled W image ============
// image[site][(v*3+tm)*64 + j][granule (o ^ (j&7))][16B]  ; octet o holds i = 8o..8o+7
__global__ void prep_w(const float* __restrict__ bulk, char* __restrict__ wsd) {
    const int s  = blockIdx.x;
    const int t  = threadIdx.x;       // 256
    const int j  = t >> 2;
    const int op = t & 3;
    const float* bs = bulk + (size_t)s * 8192 + j;   // + i*128 + v*64
    char* dsite = wsd + (size_t)s * WSITE;
    #pragma unroll
    for (int v = 0; v < 2; ++v) {
        #pragma unroll
        for (int oo = 0; oo < 2; ++oo) {
            const int o = op * 2 + oo;
            uint h[3][8];
            #pragma unroll
            for (int e = 0; e < 8; ++e) {
                const float x = bs[(o * 8 + e) * 128 + v * 64];
                const uint  u1 = __float_as_uint(x) & 0xffff0000u;
                const float r1 = x - __uint_as_float(u1);
                const uint  u2 = __float_as_uint(r1) & 0xffff0000u;
                const float r2 = r1 - __uint_as_float(u2);
                const uint  u3 = __float_as_uint(r2) & 0xffff0000u;
                h[0][e] = u1; h[1][e] = u2; h[2][e] = u3;
            }
            char* base = dsite + (size_t)j * 128 + ((o ^ (j & 7)) * 16);
            #pragma unroll
            for (int tm = 0; tm < 3; ++tm) {
                i32x4 q;
                q.x = (int)((h[tm][0] >> 16) | (h[tm][1] & 0xffff0000u));
                q.y = (int)((h[tm][2] >> 16) | (h[tm][3] & 0xffff0000u));
                q.z = (int)((h[tm][4] >> 16) | (h[tm][5] & 0xffff0000u));
                q.w = (int)((h[tm][6] >> 16) | (h[tm][7] & 0xffff0000u));
                *(i32x4*)(base + (v * 3 + tm) * 8192) = q;
            }
        }
    }
}

// ============ prepass 2: pack per-batch v bits into 4 uints via ballot ============
__global__ void prep_mask(const int* __restrict__ cfg, uint* __restrict__ msk) {
    const int w = threadIdx.x >> 6, l = threadIdx.x & 63;   // 256 thr = 4 waves
    const int b = blockIdx.x * 2 + (w >> 1);
    const int half = w & 1;
    int idx = half * 64 + l + 1;
    if (idx > 127) idx = 127;
    const int v = cfg[b * NSITES + idx];
    const unsigned long long bal = __ballot(v != 0);
    if (l == 0) {
        msk[b * 4 + half * 2]     = (uint)(bal & 0xffffffffu);
        msk[b * 4 + half * 2 + 1] = (uint)(bal >> 32);
    }
}

// ============ main kernel: 4 consumer waves + 4 producer waves ============

#define PUBLISH(PW) do { \
    uint pa_[3][4]; \
    _Pragma("unroll") \
    for (int r = 0; r < 4; ++r) { \
        const float x_ = eg0[r]; \
        const uint  u1_ = __float_as_uint(x_) & 0xffff0000u; \
        const float r1_ = x_ - __uint_as_float(u1_); \
        const uint  u2_ = __float_as_uint(r1_) & 0xffff0000u; \
        const float r2_ = r1_ - __uint_as_float(u2_); \
        pa_[0][r] = u1_; pa_[1][r] = u2_; \
        pa_[2][r] = __float_as_uint(r2_) & 0xffff0000u; \
    } \
    _Pragma("unroll") \
    for (int tm = 0; tm < 3; ++tm) { \
        i32x2 d_; \
        d_.x = (int)((pa_[tm][0] >> 16) | (pa_[tm][1] & 0xffff0000u)); \
        d_.y = (int)((pa_[tm][2] >> 16) | (pa_[tm][3] & 0xffff0000u)); \
        *(i32x2*)(smem + aW[PW] + tm * 2048) = d_; \
    } \
    _Pragma("unroll") \
    for (int r = 0; r < 4; ++r) { \
        const float x_ = eg1[r]; \
        const uint  u1_ = __float_as_uint(x_) & 0xffff0000u; \
        const float r1_ = x_ - __uint_as_float(u1_); \
        const uint  u2_ = __float_as_uint(r1_) & 0xffff0000u; \
        const float r2_ = r1_ - __uint_as_float(u2_); \
        pa_[0][r] = u1_; pa_[1][r] = u2_; \
        pa_[2][r] = __float_as_uint(r2_) & 0xffff0000u; \
    } \
    _Pragma("unroll") \
    for (int tm = 0; tm < 3; ++tm) { \
        i32x2 d_; \
        d_.x = (int)((pa_[tm][0] >> 16) | (pa_[tm][1] & 0xffff0000u)); \
        d_.y = (int)((pa_[tm][2] >> 16) | (pa_[tm][3] & 0xffff0000u)); \
        *(i32x2*)(smem + aW[PW] + 6144 + tm * 2048) = d_; \
    } \
} while (0)

#define MSTEP(TW, TE) \
    _Pragma("unroll") \
    for (int ks = 0; ks < 2; ++ks) { \
        acc00 = MFMA_BF16(Af[0][TW][ks], Bf[0][TE][ks], acc00, 0, 0, 0); \
        acc01 = MFMA_BF16(Af[1][TW][ks], Bf[0][TE][ks], acc01, 0, 0, 0); \
        acc10 = MFMA_BF16(Af[0][TW][ks], Bf[1][TE][ks], acc10, 0, 0, 0); \
        acc11 = MFMA_BF16(Af[1][TW][ks], Bf[1][TE][ks], acc11, 0, 0, 0); \
    }

#define SITE_BODY(S, II, PAR, DO_SCALE, DO_MAX) do { \
  if (w < 4) { \
    bf16x8 Af[2][3][2], Bf[2][3][2]; \
    _Pragma("unroll") for (int vv = 0; vv < 2; ++vv) \
    _Pragma("unroll") for (int tm = 0; tm < 3; ++tm) \
    _Pragma("unroll") for (int ks = 0; ks < 2; ++ks) \
        Af[vv][tm][ks] = *(const bf16x8*)(smem + aA[PAR][ks] + (vv * 3 + tm) * 8192); \
    _Pragma("unroll") for (int gg = 0; gg < 2; ++gg) \
    _Pragma("unroll") for (int tm = 0; tm < 3; ++tm) \
    _Pragma("unroll") for (int ks = 0; ks < 2; ++ks) \
        Bf[gg][tm][ks] = *(const bf16x8*)(smem + aB[PAR][ks] + (gg * 3 + tm) * 2048); \
    f32x4 acc00 = {0.f,0.f,0.f,0.f}, acc01 = {0.f,0.f,0.f,0.f}; \
    f32x4 acc10 = {0.f,0.f,0.f,0.f}, acc11 = {0.f,0.f,0.f,0.f}; \
    __builtin_amdgcn_s_setprio(1); \
    MSTEP(2,0) MSTEP(1,1) MSTEP(0,2) MSTEP(1,0) MSTEP(0,1) MSTEP(0,0) \
    __builtin_amdgcn_s_setprio(0); \
    const bool v0_ = ((mwa >> (II)) & 1u) != 0u; \
    const bool v1_ = ((mwb >> (II)) & 1u) != 0u; \
    eg0.x = v0_ ? acc01.x : acc00.x;  eg0.y = v0_ ? acc01.y : acc00.y; \
    eg0.z = v0_ ? acc01.z : acc00.z;  eg0.w = v0_ ? acc01.w : acc00.w; \
    eg1.x = v1_ ? acc11.x : acc10.x;  eg1.y = v1_ ? acc11.y : acc10.y; \
    eg1.z = v1_ ? acc11.z : acc10.z;  eg1.w = v1_ ? acc11.w : acc10.w; \
    if (DO_SCALE) { \
      f32x4 m4a = *(const f32x4*)(smem + RED_OFF + lb * 16); \
      f32x4 m4b = *(const f32x4*)(smem + RED_OFF + 256 + lb * 16); \
      const float ma = fmaxf(fmaxf(m4a.x, m4a.y), fmaxf(m4a.z, m4a.w)); \
      const float mb = fmaxf(fmaxf(m4b.x, m4b.y), fmaxf(m4b.z, m4b.w)); \
      const int ea = (__float_as_int(ma) >> 23) & 255; \
      const int eb = (__float_as_int(mb) >> 23) & 255; \
      const float sa = __int_as_float((254 - ea) << 23); \
      const float sb = __int_as_float((254 - eb) << 23); \
      ls0 += (float)(ea - 127) * 0.6931471805599453f; \
      ls1 += (float)(eb - 127) * 0.6931471805599453f; \
      eg0.x *= sa; eg0.y *= sa; eg0.z *= sa; eg0.w *= sa; \
      eg1.x *= sb; eg1.y *= sb; eg1.z *= sb; eg1.w *= sb; \
    } \
    if (DO_MAX) { \
      float ma = fmaxf(fmaxf(fabsf(eg0.x), fabsf(eg0.y)), fmaxf(fabsf(eg0.z), fabsf(eg0.w))); \
      float mb = fmaxf(fmaxf(fabsf(eg1.x), fabsf(eg1.y)), fmaxf(fabsf(eg1.z), fabsf(eg1.w))); \
      ma = fmaxf(ma, __shfl_xor(ma, 16)); ma = fmaxf(ma, __shfl_xor(ma, 32)); \
      mb = fmaxf(mb, __shfl_xor(mb, 16)); mb = fmaxf(mb, __shfl_xor(mb, 32)); \
      if (lg == 0) { \
        *(float*)(smem + RED_OFF + lb * 16 + jt * 4) = ma; \
        *(float*)(smem + RED_OFF + 256 + lb * 16 + jt * 4) = mb; \
      } \
    } \
    PUBLISH((PAR) ^ 1); \
  } else if ((S) + 1 < NBULK) { \
    const char* sp_ = ws + (size_t)((S) + 1) * WSITE + (w - 4) * 12288 + l * 16; \
    char* dp_ = smem + (((PAR) ^ 1) * WSITE) + (w - 4) * 12288; \
    _Pragma("unroll") \
    for (int u = 0; u < 12; ++u) \
      __builtin_amdgcn_global_load_lds( \
          (const __attribute__((address_space(1))) void*)(sp_ + u * 1024), \
          (__attribute__((address_space(3))) void*)(dp_ + u * 1024), 16, 0, 0); \
  } \
  __syncthreads(); \
} while (0)

#define RUN_CHUNK(CB, MWE0, MWE1, CNT, SC0, MXE) { \
  const uint mwa = (MWE0), mwb = (MWE1); \
  _Pragma("unroll 1") \
  for (int i2 = 0; i2 < (CNT); i2 += 2) { \
    SITE_BODY((CB) * 32 + i2,     i2,     0, ((SC0) && i2 == 0),           false); \
    SITE_BODY((CB) * 32 + i2 + 1, i2 + 1, 1, false, ((MXE) && i2 == (CNT) - 2)); \
  } \
}

__global__ __launch_bounds__(512, 2) void mps_main(
    const int*   __restrict__ cfg,
    const float* __restrict__ left,
    const float* __restrict__ right,
    const char*  __restrict__ ws,
    float*       __restrict__ out)
{
    extern __shared__ __align__(16) char smem[];
    const int t  = threadIdx.x;
    const int w  = t >> 6, l = t & 63;
    const int lg = l >> 4, lb = l & 15;
    const int jt = w & 3;
    const int bbase = blockIdx.x * 32;
    const int b0 = bbase + lb, b1 = bbase + 16 + lb;

    // precomputed LDS byte addresses (consumer)
    int aA[2][2], aB[2][2], aW[2];
    {
        const int key = lb & 7;
        const int s0 = ((0 + lg) ^ key) * 16;
        const int s1 = ((4 + lg) ^ key) * 16;
        const int jrow = jt * 16 + lb;
        aA[0][0] = jrow * 128 + s0;   aA[0][1] = jrow * 128 + s1;
        aA[1][0] = aA[0][0] + WSITE;  aA[1][1] = aA[0][1] + WSITE;
        aB[0][0] = EBUF0 + lb * 128 + s0;  aB[0][1] = EBUF0 + lb * 128 + s1;
        aB[1][0] = aB[0][0] + EBUF_SZ;     aB[1][1] = aB[0][1] + EBUF_SZ;
        aW[0] = EBUF0 + lb * 128 + (((jt * 2 + (lg >> 1)) ^ key) * 16) + (lg & 1) * 8;
        aW[1] = aW[0] + EBUF_SZ;
    }

    float ls0 = 0.f, ls1 = 0.f;
    f32x4 eg0 = {0.f,0.f,0.f,0.f}, eg1 = {0.f,0.f,0.f,0.f};
    uint4 vmg0 = {0,0,0,0}, vmg1 = {0,0,0,0};

    if (w < 4) {
        const uint* mp = (const uint*)(ws + WMASK_OFF);
        vmg0 = *(const uint4*)(mp + (size_t)b0 * 4);
        vmg1 = *(const uint4*)(mp + (size_t)b1 * 4);
        const int c00 = cfg[b0 * NSITES], c01 = cfg[b1 * NSITES];
        const int jout = jt * 16 + lg * 4;
        #pragma unroll
        for (int r = 0; r < 4; ++r) {
            eg0[r] = left[c00 * BOND + jout + r];
            eg1[r] = left[c01 * BOND + jout + r];
        }
        PUBLISH(0);
    } else {
        // stage site 0 into W buffer 0
        const char* sp_ = ws + (w - 4) * 12288 + l * 16;
        char* dp_ = smem + (w - 4) * 12288;
        #pragma unroll
        for (int u = 0; u < 12; ++u)
            __builtin_amdgcn_global_load_lds(
                (const __attribute__((address_space(1))) void*)(sp_ + u * 1024),
                (__attribute__((address_space(3))) void*)(dp_ + u * 1024), 16, 0, 0);
    }
    __syncthreads();

    RUN_CHUNK(0, vmg0.x, vmg1.x, 32, false, true)
    RUN_CHUNK(1, vmg0.y, vmg1.y, 32, true,  true)
    RUN_CHUNK(2, vmg0.z, vmg1.z, 32, true,  true)
    RUN_CHUNK(3, vmg0.w, vmg1.w, 30, true,  false)

    // ---- epilogue: contract with right tensor, reduce across waves ----
    if (w < 4) {
        const int vl0 = cfg[b0 * NSITES + 127], vl1 = cfg[b1 * NSITES + 127];
        const int jout = jt * 16 + lg * 4;
        float p0 = eg0.x * right[(jout + 0) * 2 + vl0] + eg0.y * right[(jout + 1) * 2 + vl0]
                 + eg0.z * right[(jout + 2) * 2 + vl0] + eg0.w * right[(jout + 3) * 2 + vl0];
        float p1 = eg1.x * right[(jout + 0) * 2 + vl1] + eg1.y * right[(jout + 1) * 2 + vl1]
                 + eg1.z * right[(jout + 2) * 2 + vl1] + eg1.w * right[(jout + 3) * 2 + vl1];
        p0 += __shfl_xor(p0, 16); p0 += __shfl_xor(p0, 32);
        p1 += __shfl_xor(p1, 16); p1 += __shfl_xor(p1, 32);
        if (lg == 0) {
            *(float*)(smem + RED_OFF + lb * 16 + jt * 4) = p0;
            *(float*)(smem + RED_OFF + 256 + lb * 16 + jt * 4) = p1;
        }
    }
    __syncthreads();
    if (w == 0 && l < 16) {
        f32x4 q0 = *(const f32x4*)(smem + RED_OFF + lb * 16);
        f32x4 q1 = *(const f32x4*)(smem + RED_OFF + 256 + lb * 16);
        const float s0 = (q0.x + q0.y) + (q0.z + q0.w);
        const float s1 = (q1.x + q1.y) + (q1.z + q1.w);
        out[b0] = 2.0f * (ls0 + logf(fmaxf(fabsf(s0), 1e-30f)));
        out[b1] = 2.0f * (ls1 + logf(fmaxf(fabsf(s1), 1e-30f)));
    }
}

// ================= fallback fp32 kernel (R0, known-good) =================
#define WPB     16
#define TPB     (WPB * 64)
#define SITE_ELTS (BOND * 2 * BOND)

__global__ __launch_bounds__(TPB, 2) void mps_logamp_fp32(
    const int*   __restrict__ cfg, const float* __restrict__ left,
    const float* __restrict__ bulk, const float* __restrict__ right,
    float* __restrict__ out)
{
    __shared__ float Abuf[2][SITE_ELTS];
    __shared__ float envs[WPB][BOND];
    __shared__ int   cfgs[WPB * NSITES];
    const int t = threadIdx.x;
    const int w = t >> 6, l = t & 63;
    const int bbase = blockIdx.x * WPB;
    const int b = bbase + w;
    cfgs[t] = cfg[bbase * NSITES + t];
    cfgs[t + TPB] = cfg[bbase * NSITES + t + TPB];
    { const float4* src = (const float4*)bulk; float4* dst = (float4*)(&Abuf[0][0]);
      dst[t] = src[t]; dst[t + TPB] = src[t + TPB]; }
    __syncthreads();
    const int c0 = cfgs[w * NSITES];
    float e = left[c0 * BOND + l];
    float m = fabsf(e);
    #pragma unroll
    for (int k = 32; k; k >>= 1) m = fmaxf(m, __shfl_xor(m, k));
    m = fmaxf(m, 1e-30f);
    e = e / m;
    float ls = logf(m);
    envs[w][l] = e;
    for (int s = 0; s < NBULK; ++s) {
        const int cur = s & 1, nxt = cur ^ 1;
        const bool pf = (s + 1 < NBULK);
        float4 p0, p1;
        if (pf) { const float4* src = (const float4*)(bulk + (size_t)(s + 1) * SITE_ELTS);
                  p0 = src[t]; p1 = src[t + TPB]; }
        const int v = cfgs[w * NSITES + (s + 1)];
        const float* Ap = &Abuf[cur][v * BOND + l];
        const float* ev = &envs[w][0];
        float acc = 0.0f;
        #pragma unroll
        for (int i = 0; i < BOND; i += 4) {
            const float4 e4 = *(const float4*)(ev + i);
            acc = fmaf(e4.x, Ap[(i + 0) * 128], acc);
            acc = fmaf(e4.y, Ap[(i + 1) * 128], acc);
            acc = fmaf(e4.z, Ap[(i + 2) * 128], acc);
            acc = fmaf(e4.w, Ap[(i + 3) * 128], acc);
        }
        float mm = fabsf(acc);
        #pragma unroll
        for (int k = 32; k; k >>= 1) mm = fmaxf(mm, __shfl_xor(mm, k));
        mm = fmaxf(mm, 1e-30f);
        acc = acc / mm;
        ls += logf(mm);
        if (pf) { float4* dst = (float4*)(&Abuf[nxt][0]); dst[t] = p0; dst[t + TPB] = p1; }
        envs[w][l] = acc;
        e = acc;
        __syncthreads();
    }
    const int vl = cfgs[w * NSITES + (NSITES - 1)];
    float p = e * right[l * 2 + vl];
    #pragma unroll
    for (int k = 32; k; k >>= 1) p += __shfl_xor(p, k);
    const float am = fmaxf(fabsf(p), 1e-30f);
    if (l == 0) out[b] = 2.0f * (ls + logf(am));
}

extern "C" void kernel_launch(void* const* d_in, const int* in_sizes, int n_in,
                              void* d_out, int out_size, void* d_ws, size_t ws_size,
                              hipStream_t stream) {
    const int*   cfg   = (const int*)d_in[0];
    const float* left  = (const float*)d_in[1];
    const float* bulk  = (const float*)d_in[2];
    const float* right = (const float*)d_in[3];
    float*       out   = (float*)d_out;

    if (ws_size >= WS_NEED) {
        hipFuncSetAttribute((const void*)mps_main,
                            hipFuncAttributeMaxDynamicSharedMemorySize, SMEM_SZ);
        hipLaunchKernelGGL(prep_w, dim3(NBULK), dim3(256), 0, stream,
                           bulk, (char*)d_ws);
        hipLaunchKernelGGL(prep_mask, dim3(BATCH / 2), dim3(256), 0, stream,
                           cfg, (uint*)((char*)d_ws + WMASK_OFF));
        hipLaunchKernelGGL(mps_main, dim3(BATCH / 32), dim3(512), SMEM_SZ, stream,
                           cfg, left, right, (const char*)d_ws, out);
    } else {
        hipLaunchKernelGGL(mps_logamp_fp32, dim3(BATCH / WPB), dim3(TPB), 0, stream,
                           cfg, left, bulk, right, out);
    }
}